// Round 7
// baseline (253.572 us; speedup 1.0000x reference)
//
#include <hip/hip_runtime.h>
#include <stdint.h>

#define NBLK 128           // sequence blocks
#define KDIM 512

typedef __attribute__((ext_vector_type(8))) short short8;
typedef __attribute__((ext_vector_type(4))) float f32x4;
typedef unsigned short u16;

__device__ __forceinline__ u16 f2bf(float f) {
  unsigned u = __float_as_uint(f);
  u = u + 0x7fffu + ((u >> 16) & 1u);
  return (u16)(u >> 16);
}

__device__ __forceinline__ void g2l16(const void* g, void* l) {
  __builtin_amdgcn_global_load_lds(
      (__attribute__((address_space(1))) void*)(g),
      (__attribute__((address_space(3))) void*)(l), 16, 0, 0);
}

// ---------------- K0a: fp32 -> bf16, de-interleave batch (8 elems/thread) --------
// in : (s,b,e) fp32, rows (s*2+b)*512 ; out: [r'=b*8192+s][e] bf16
__global__ void conv_inputs(const float* __restrict__ q, const float* __restrict__ k,
                            const float* __restrict__ v, u16* __restrict__ qb,
                            u16* __restrict__ kb, u16* __restrict__ vb) {
  const float* src[3] = {q, k, v};
  u16* dst[3] = {qb, kb, vb};
  int t = blockIdx.x * 256 + threadIdx.x;    // 0..1048575
  int o = t * 8;                             // output element index (8.4M total)
  int b = o >> 22;
  int s = (o >> 9) & 8191;
  int e = o & 511;
  const float* p = src[blockIdx.y] + ((s * 2 + b) * 512 + e);
  float4 v0 = *(const float4*)(p);
  float4 v1 = *(const float4*)(p + 4);
  short8 r;
  r[0] = (short)f2bf(v0.x); r[1] = (short)f2bf(v0.y);
  r[2] = (short)f2bf(v0.z); r[3] = (short)f2bf(v0.w);
  r[4] = (short)f2bf(v1.x); r[5] = (short)f2bf(v1.y);
  r[6] = (short)f2bf(v1.z); r[7] = (short)f2bf(v1.w);
  *(short8*)(dst[blockIdx.y] + o) = r;
}

// ---------------- K0b: weight prep ----------------
__global__ void prep_weights(const float* __restrict__ qw, const float* __restrict__ kw,
                             const float* __restrict__ vw, const float* __restrict__ ow,
                             u16* __restrict__ wqt, u16* __restrict__ wkt,
                             u16* __restrict__ wvt, u16* __restrict__ owb) {
  int t = blockIdx.x * 256 + threadIdx.x;    // 0..65535
  int y = blockIdx.y;
  if (y < 3) {
    const float* w = (y == 0) ? qw : (y == 1) ? kw : vw;
    u16* dstp = (y == 0) ? wqt : (y == 1) ? wkt : wvt;
    int c = t >> 7;              // 0..511
    int e4 = (t & 127) * 4;
    int h = c >> 6, d = c & 63;
    const float* base = w + h * (512 * 64) + d;
    ushort4 r;
    r.x = f2bf(base[(e4 + 0) * 64]);
    r.y = f2bf(base[(e4 + 1) * 64]);
    r.z = f2bf(base[(e4 + 2) * 64]);
    r.w = f2bf(base[(e4 + 3) * 64]);
    *(ushort4*)(dstp + c * 512 + e4) = r;
  } else {
    float4 val = *(const float4*)(ow + t * 4);
    ushort4 r;
    r.x = f2bf(val.x); r.y = f2bf(val.y); r.z = f2bf(val.z); r.w = f2bf(val.w);
    *(ushort4*)(owb + t * 4) = r;
  }
}

// ---------------- GEMM core: C[M][N] = A[M][K] * BT[N][K]^T (bf16, K=512, BK=64) ---
// g2l16 DMA staging (round-3 measured-good), 2 barriers per k-step, but BK=64:
// 8 k-iterations, 32 MFMA per barrier -> half the structural vmcnt drains.
// Tile rows are 128 B (8 chunks of 16 B); chunk c stored at c^(r&7) -> DMA writes
// sequential, fragment ds_read_b128 phases hit all 32 banks.
// MODE 0: u16 out [b][h][s][d], bias by n. MODE 1: u16 out V^T [b][hd][s], bias by m.
// MODE 2: fp32 out (s,b,e), bias by n.
template <int MODE>
__device__ __forceinline__ void gemm_core(const u16* __restrict__ A, const u16* __restrict__ BT,
                                          const float* __restrict__ bias, void* __restrict__ dstv,
                                          int tileM, int tileN, u16* sh) {
  const int t = threadIdx.x;
  const int lane = t & 63, w = t >> 6;
  const int l15 = lane & 15, quad = lane >> 4;
  const int wm = w >> 1, wn = w & 1;

  f32x4 acc[4][4];
#pragma unroll
  for (int i = 0; i < 4; ++i)
#pragma unroll
    for (int j = 0; j < 4; ++j) acc[i][j] = (f32x4){0.f, 0.f, 0.f, 0.f};

  // DMA slots: 4 per thread per side; slot s -> row s>>3, stored chunk s&7,
  // source chunk g = (s&7)^(row&7)
  const u16* aS[4]; const u16* bS[4];
#pragma unroll
  for (int i = 0; i < 4; ++i) {
    const int s = t + i * 256;
    const int r = s >> 3, g = (s & 7) ^ (r & 7);
    aS[i] = A + (size_t)(tileM + r) * KDIM + g * 8;
    bS[i] = BT + (size_t)(tileN + r) * KDIM + g * 8;
  }

  for (int k0 = 0; k0 < KDIM; k0 += 64) {
    __syncthreads();
#pragma unroll
    for (int i = 0; i < 4; ++i) g2l16(aS[i] + k0, sh + (t + i * 256) * 8);
#pragma unroll
    for (int i = 0; i < 4; ++i) g2l16(bS[i] + k0, sh + 8192 + (t + i * 256) * 8);
    __syncthreads();

#pragma unroll
    for (int sub = 0; sub < 2; ++sub) {
      short8 af[4], bf[4];
#pragma unroll
      for (int mt = 0; mt < 4; ++mt) {
        const int ra = wm * 64 + mt * 16 + l15;
        af[mt] = *(const short8*)(sh + ra * 64 + (((sub * 4 + quad) ^ (ra & 7)) << 3));
      }
#pragma unroll
      for (int nt = 0; nt < 4; ++nt) {
        const int rb = wn * 64 + nt * 16 + l15;
        bf[nt] = *(const short8*)(sh + 8192 + rb * 64 + (((sub * 4 + quad) ^ (rb & 7)) << 3));
      }
#pragma unroll
      for (int mt = 0; mt < 4; ++mt)
#pragma unroll
        for (int nt = 0; nt < 4; ++nt)
          acc[mt][nt] = __builtin_amdgcn_mfma_f32_16x16x32_bf16(af[mt], bf[nt], acc[mt][nt], 0, 0, 0);
    }
  }
  __syncthreads();   // staging LDS fully consumed before epilogue reuse

  if (MODE == 0 || MODE == 1) {
    // C-tile (u16, 128x128) -> LDS with chunk swizzle, then coalesced 16B stores
#pragma unroll
    for (int mt = 0; mt < 4; ++mt)
#pragma unroll
      for (int nt = 0; nt < 4; ++nt)
#pragma unroll
        for (int rr = 0; rr < 4; ++rr) {
          const int lrow = wm * 64 + mt * 16 + quad * 4 + rr;
          const int col = wn * 64 + nt * 16 + l15;
          float v = acc[mt][nt][rr] + (MODE == 0 ? bias[tileN + col] : bias[tileM + lrow]);
          const int ch = col >> 3;
          sh[lrow * 128 + ((ch ^ (lrow & 7)) << 3) + (col & 7)] = f2bf(v);
        }
    __syncthreads();
#pragma unroll
    for (int p = 0; p < 8; ++p) {
      const int idx = p * 256 + t;
      const int row = idx >> 4, c = idx & 15;
      short8 vch = *(const short8*)(sh + row * 128 + ((c ^ (row & 7)) << 3));
      if (MODE == 0) {
        const int m = tileM + row, b = m >> 13, s = m & 8191;
        const int n0 = tileN + c * 8, hh = n0 >> 6, d = n0 & 63;
        *(short8*)((u16*)dstv + (((b * 8 + hh) * 8192 + s) * 64 + d)) = vch;
      } else {
        const int hd = tileM + row;
        const int n0 = tileN + c * 8, b = n0 >> 13, s = n0 & 8191;
        *(short8*)((u16*)dstv + ((b * 512 + hd) * 8192 + s)) = vch;
      }
    }
  } else {
    // fp32 C-tile in two 64-row halves (32 KB each)
    float* Cf = (float*)sh;   // 8192 floats
#pragma unroll
    for (int half = 0; half < 2; ++half) {
      if (wm == half) {
#pragma unroll
        for (int mt = 0; mt < 4; ++mt)
#pragma unroll
          for (int nt = 0; nt < 4; ++nt)
#pragma unroll
            for (int rr = 0; rr < 4; ++rr) {
              const int lrow = mt * 16 + quad * 4 + rr;
              const int col = wn * 64 + nt * 16 + l15;
              float v = acc[mt][nt][rr] + bias[tileN + col];
              const int ch = col >> 2;
              Cf[lrow * 128 + ((ch ^ ((lrow & 7) << 2)) << 2) + (col & 3)] = v;
            }
      }
      __syncthreads();
#pragma unroll
      for (int p = 0; p < 8; ++p) {
        const int idx = p * 256 + t;
        const int row = idx >> 5, c = idx & 31;
        float4 v4 = *(const float4*)(Cf + row * 128 + ((c ^ ((row & 7) << 2)) << 2));
        const int m = tileM + half * 64 + row;
        const int s = m & 8191, b = m >> 13;
        *(float4*)((float*)dstv + ((s * 2 + b) * 512 + tileN + c * 4)) = v4;
      }
      __syncthreads();
    }
  }
}

// merged QKV projection: z=0 Q, z=1 K, z=2 V^T. XCD swizzle: blocks sharing
// A-rows share an XCD L2.
__global__ __launch_bounds__(256, 4)
void gemm_qkv(const u16* __restrict__ qb, const u16* __restrict__ kb, const u16* __restrict__ vb,
              const u16* __restrict__ WqT, const u16* __restrict__ WkT, const u16* __restrict__ WvT,
              const float* __restrict__ qbi, const float* __restrict__ kbi, const float* __restrict__ vbi,
              u16* __restrict__ Qb, u16* __restrict__ Kb, u16* __restrict__ Vt) {
  __shared__ __align__(16) u16 sh[16384];
  const int id = blockIdx.x + blockIdx.y * 4;
  const int xs = (id >> 3) & 3;
  const int ys = (id & 7) * 16 + (id >> 5);
  const int z = blockIdx.z;
  if (z == 0)      gemm_core<0>(qb, WqT, qbi, Qb, ys * 128, xs * 128, sh);
  else if (z == 1) gemm_core<0>(kb, WkT, kbi, Kb, ys * 128, xs * 128, sh);
  else             gemm_core<1>(WvT, vb, vbi, Vt, xs * 128, ys * 128, sh);
}

__global__ __launch_bounds__(256, 4)
void gemm_out_k(const u16* __restrict__ AO, const u16* __restrict__ OW,
                const float* __restrict__ ob, float* __restrict__ out) {
  __shared__ __align__(16) u16 sh[16384];
  const int id = blockIdx.x + blockIdx.y * 4;
  const int xs = (id >> 3) & 3;
  const int ys = (id & 7) * 16 + (id >> 5);
  gemm_core<2>(AO, OW, ob, out, ys * 128, xs * 128, sh);
}

// ---------------- K2: block-sparse attention (round-2 measured-good form) ---------
// grid 2048x1. bh = blk&15 (XCD L2 locality), nb = blk>>4.
// Qb/Kb: [b][h][s][d] bf16, Vt: [b][h][d][s] bf16. AO out: [b*8192+s][h*64+d] bf16.
__global__ __launch_bounds__(256, 5)
void attn(const u16* __restrict__ Qb, const u16* __restrict__ Kb,
          const u16* __restrict__ Vt, const int* __restrict__ ridx,
          u16* __restrict__ AO) {
  __shared__ u16 Ks[64 * 64];   // [key][d], 16B-chunk XOR swizzle (r&7)
  __shared__ u16 Vs[64 * 64];   // [d][key]
  __shared__ u16 Ps[64 * 64];   // [q][key], wave-private rows
  const int blk = blockIdx.x;
  const int bh = blk & 15, nb = blk >> 4;
  const int b = bh >> 3, h = bh & 7;
  const int t = threadIdx.x, lane = t & 63, w = t >> 6;
  const int l15 = lane & 15, quad = lane >> 4;

  int bidx[8];
  bidx[0] = 0; bidx[1] = 1;
  bidx[2] = (nb + NBLK - 1) & (NBLK - 1);
  bidx[3] = nb;
  bidx[4] = (nb + 1) & (NBLK - 1);
  bidx[5] = ridx[nb * 3 + 0];
  bidx[6] = ridx[nb * 3 + 1];
  bidx[7] = ridx[nb * 3 + 2];

  const u16* qrow = Qb + (bh * 8192 + nb * 64 + w * 16 + l15) * 64;
  short8 aq0 = *(const short8*)(qrow + quad * 8);
  short8 aq1 = *(const short8*)(qrow + 32 + quad * 8);

  const int s0 = t, s1 = t + 256;
  const int r0 = s0 >> 3, c0 = (s0 & 7) ^ (r0 & 7);
  const int r1 = s1 >> 3, c1 = (s1 & 7) ^ (r1 & 7);
  const u16* Kbase = Kb + bh * 8192 * 64;
  const u16* Vbase = Vt + (bh * 64) * 8192;

  f32x4 oacc[4];
#pragma unroll
  for (int i = 0; i < 4; ++i) oacc[i] = (f32x4){0.f, 0.f, 0.f, 0.f};
  float lsum[4] = {0.f, 0.f, 0.f, 0.f};

  for (int m = 0; m < 8; ++m) {
    const int kb0 = bidx[m] * 64;
    __syncthreads();
    g2l16(Kbase + (kb0 + r0) * 64 + c0 * 8, Ks + s0 * 8);
    g2l16(Kbase + (kb0 + r1) * 64 + c1 * 8, Ks + s1 * 8);
    g2l16(Vbase + r0 * 8192 + kb0 + c0 * 8, Vs + s0 * 8);
    g2l16(Vbase + r1 * 8192 + kb0 + c1 * 8, Vs + s1 * 8);
    __syncthreads();

    f32x4 s[4];
#pragma unroll
    for (int i = 0; i < 4; ++i) s[i] = (f32x4){0.f, 0.f, 0.f, 0.f};
#pragma unroll
    for (int nt = 0; nt < 4; ++nt) {
      const int key = nt * 16 + l15;
      const u16* kr = Ks + key * 64;
      short8 bk0 = *(const short8*)(kr + ((quad ^ (key & 7)) << 3));
      short8 bk1 = *(const short8*)(kr + (((4 + quad) ^ (key & 7)) << 3));
      s[nt] = __builtin_amdgcn_mfma_f32_16x16x32_bf16(aq0, bk0, s[nt], 0, 0, 0);
      s[nt] = __builtin_amdgcn_mfma_f32_16x16x32_bf16(aq1, bk1, s[nt], 0, 0, 0);
    }

#pragma unroll
    for (int nt = 0; nt < 4; ++nt) {
      const int key = nt * 16 + l15;
      const int cp = key >> 3;
#pragma unroll
      for (int rr = 0; rr < 4; ++rr) {
        float p = __expf(s[nt][rr] * 0.125f);
        lsum[rr] += p;
        const int q = w * 16 + quad * 4 + rr;
        Ps[q * 64 + (((cp ^ (q & 7)) << 3) | (key & 7))] = f2bf(p);
      }
    }

    const int q2 = w * 16 + l15;
    const u16* pr = Ps + q2 * 64;
    short8 ap0 = *(const short8*)(pr + ((quad ^ (q2 & 7)) << 3));
    short8 ap1 = *(const short8*)(pr + (((4 + quad) ^ (q2 & 7)) << 3));
#pragma unroll
    for (int nt = 0; nt < 4; ++nt) {
      const int d = nt * 16 + l15;
      const u16* vr = Vs + d * 64;
      short8 bv0 = *(const short8*)(vr + ((quad ^ (d & 7)) << 3));
      short8 bv1 = *(const short8*)(vr + (((4 + quad) ^ (d & 7)) << 3));
      oacc[nt] = __builtin_amdgcn_mfma_f32_16x16x32_bf16(ap0, bv0, oacc[nt], 0, 0, 0);
      oacc[nt] = __builtin_amdgcn_mfma_f32_16x16x32_bf16(ap1, bv1, oacc[nt], 0, 0, 0);
    }
  }

#pragma unroll
  for (int msk = 1; msk < 16; msk <<= 1)
#pragma unroll
    for (int rr = 0; rr < 4; ++rr) lsum[rr] += __shfl_xor(lsum[rr], msk, 64);
  float inv[4];
#pragma unroll
  for (int rr = 0; rr < 4; ++rr) inv[rr] = __builtin_amdgcn_rcpf(lsum[rr]);

#pragma unroll
  for (int nt = 0; nt < 4; ++nt) {
    const int cc = h * 64 + nt * 16 + l15;
#pragma unroll
    for (int rr = 0; rr < 4; ++rr) {
      const int s = nb * 64 + w * 16 + quad * 4 + rr;
      AO[(b * 8192 + s) * 512 + cc] = f2bf(oacc[nt][rr] * inv[rr]);
    }
  }
}

// ---------------- launch ----------------
extern "C" void kernel_launch(void* const* d_in, const int* in_sizes, int n_in,
                              void* d_out, int out_size, void* d_ws, size_t ws_size,
                              hipStream_t stream) {
  const float* q   = (const float*)d_in[0];
  const float* k   = (const float*)d_in[1];
  const float* v   = (const float*)d_in[2];
  const float* qw  = (const float*)d_in[3];
  const float* kw  = (const float*)d_in[4];
  const float* vw  = (const float*)d_in[5];
  const float* qbi = (const float*)d_in[6];
  const float* kbi = (const float*)d_in[7];
  const float* vbi = (const float*)d_in[8];
  const float* ow  = (const float*)d_in[9];
  const float* ob  = (const float*)d_in[10];
  const int*   ri  = (const int*)d_in[11];

  char* ws = (char*)d_ws;
  const size_t MB1 = 1024 * 1024;
  u16* qbuf = (u16*)(ws + 0);
  u16* kbuf = (u16*)(ws + 16 * MB1);
  u16* vbuf = (u16*)(ws + 32 * MB1);
  u16* AO   = (u16*)(ws + 0);            // aliases qbuf; attn runs after q-proj consumed it
  u16* Qb   = (u16*)(ws + 48 * MB1);
  u16* Kb   = (u16*)(ws + 64 * MB1);
  u16* Vt   = (u16*)(ws + 80 * MB1);
  u16* WqT  = (u16*)(ws + 96 * MB1);
  u16* WkT  = (u16*)(ws + 96 * MB1 + 512 * 1024);
  u16* WvT  = (u16*)(ws + 97 * MB1);
  u16* OW   = (u16*)(ws + 97 * MB1 + 512 * 1024);

  conv_inputs<<<dim3(4096, 3), 256, 0, stream>>>(q, k, v, qbuf, kbuf, vbuf);
  prep_weights<<<dim3(256, 4), 256, 0, stream>>>(qw, kw, vw, ow, WqT, WkT, WvT, OW);
  gemm_qkv<<<dim3(4, 128, 3), 256, 0, stream>>>(qbuf, kbuf, vbuf, WqT, WkT, WvT,
                                                qbi, kbi, vbi, Qb, Kb, Vt);
  attn<<<2048, 256, 0, stream>>>(Qb, Kb, Vt, ri, AO);
  gemm_out_k<<<dim3(4, 128), 256, 0, stream>>>(AO, OW, ob, (float*)d_out);
}